// Round 2
// baseline (483.120 us; speedup 1.0000x reference)
//
#include <hip/hip_runtime.h>
#include <hip/hip_bf16.h>

typedef __hip_bfloat16 bf16;

#define NGRAPH 128
#define CHUNK 8      // nodes per wave in the agg kernels
#define SLAB 256     // per-wave staged edge-index capacity (avg chunk = 128)

// ---------------- degree histogram ----------------
__global__ __launch_bounds__(256) void deg_kernel(const int* __restrict__ ei,
                                                  int* __restrict__ deg, int E, int N) {
    int e = blockIdx.x * 256 + threadIdx.x;
    if (e < E) {
        int d = ei[E + e];                 // dst = ei[1][e]
        d = max(0, min(d, N - 1));
        atomicAdd(&deg[d], 1);
    }
}

// ---------------- scan: per-block sums ----------------
__global__ __launch_bounds__(256) void scan1_kernel(const int* __restrict__ deg,
                                                    int* __restrict__ bsum, int N) {
    __shared__ int tmp[256];
    int i = blockIdx.x * 256 + threadIdx.x;
    tmp[threadIdx.x] = (i < N) ? deg[i] : 0;
    __syncthreads();
    for (int off = 128; off > 0; off >>= 1) {
        if (threadIdx.x < off) tmp[threadIdx.x] += tmp[threadIdx.x + off];
        __syncthreads();
    }
    if (threadIdx.x == 0) bsum[blockIdx.x] = tmp[0];
}

// ---------------- scan: exclusive scan of block sums ----------------
__global__ __launch_bounds__(256) void scan2_kernel(const int* __restrict__ bsum,
                                                    int* __restrict__ boff, int nb) {
    __shared__ int tmp[256];
    __shared__ int carry;
    int tid = threadIdx.x;
    if (tid == 0) carry = 0;
    __syncthreads();
    for (int base = 0; base < nb; base += 256) {
        int i = base + tid;
        int v = (i < nb) ? bsum[i] : 0;
        tmp[tid] = v;
        __syncthreads();
        for (int off = 1; off < 256; off <<= 1) {
            int t = (tid >= off) ? tmp[tid - off] : 0;
            __syncthreads();
            tmp[tid] += t;
            __syncthreads();
        }
        if (i < nb) boff[i] = carry + tmp[tid] - v;
        __syncthreads();
        if (tid == 0) carry += tmp[255];
        __syncthreads();
    }
}

// ---------------- scan: per-element row_start + dinv ----------------
__global__ __launch_bounds__(256) void scan3_kernel(const int* __restrict__ deg,
                                                    const int* __restrict__ boff,
                                                    int* __restrict__ row_start,
                                                    float* __restrict__ dinv, int N) {
    __shared__ int tmp[256];
    int i = blockIdx.x * 256 + threadIdx.x;
    int v = (i < N) ? deg[i] : 0;
    tmp[threadIdx.x] = v;
    __syncthreads();
    for (int off = 1; off < 256; off <<= 1) {
        int t = (threadIdx.x >= off) ? tmp[threadIdx.x - off] : 0;
        __syncthreads();
        tmp[threadIdx.x] += t;
        __syncthreads();
    }
    if (i < N) {
        int excl = tmp[threadIdx.x] - v;
        int rs = boff[blockIdx.x] + excl;
        row_start[i] = rs;
        if (i == N - 1) row_start[N] = rs + v;
        dinv[i] = rsqrtf((float)(v + 1));   // +1 self loop
    }
}

// ---------------- CSR fill (dst-sorted src list) ----------------
__global__ __launch_bounds__(256) void fill_kernel(const int* __restrict__ ei,
                                                   const int* __restrict__ row_start,
                                                   int* __restrict__ cursor,
                                                   int* __restrict__ csr_src, int E, int N) {
    int e = blockIdx.x * 256 + threadIdx.x;
    if (e < E) {
        int s = ei[e];     s = max(0, min(s, N - 1));
        int d = ei[E + e]; d = max(0, min(d, N - 1));
        int pos = row_start[d] + atomicAdd(&cursor[d], 1);
        if (pos >= 0 && pos < E) csr_src[pos] = s;
    }
}

// ---------------- P1 = (x @ W1) * dinv  (wave-per-node-pair, grid-stride) ----------------
__global__ __launch_bounds__(256) void proj_kernel(const float* __restrict__ A,
                                                   const float* __restrict__ W,
                                                   const float* __restrict__ dinv,
                                                   bf16* __restrict__ P, int N) {
    __shared__ float Wl[4096];
    for (int i = threadIdx.x; i < 4096; i += 256) Wl[i] = W[i];
    __syncthreads();
    int lane = threadIdx.x & 63;
    int wid = (blockIdx.x * 256 + threadIdx.x) >> 6;
    int nwaves = (gridDim.x * 256) >> 6;
    int npairs = (N + 1) >> 1;
    for (int p = wid; p < npairs; p += nwaves) {
        int n0 = p * 2, n1 = n0 + 1;
        float a0 = A[(size_t)n0 * 64 + lane];
        float a1 = (n1 < N) ? A[(size_t)n1 * 64 + lane] : 0.f;
        float s0 = 0.f, s1 = 0.f;
#pragma unroll
        for (int k = 0; k < 64; ++k) {
            float w = Wl[k * 64 + lane];          // one LDS read feeds both nodes
            s0 += __shfl(a0, k) * w;
            s1 += __shfl(a1, k) * w;
        }
        P[(size_t)n0 * 64 + lane] = __float2bfloat16(s0 * dinv[n0]);
        if (n1 < N) P[(size_t)n1 * 64 + lane] = __float2bfloat16(s1 * dinv[n1]);
    }
}

// ---- unpack uint4 (8 bf16) and accumulate with weight w ----
__device__ __forceinline__ void acc_bf8(float* acc, uint4 v, float w) {
    unsigned int u[4] = {v.x, v.y, v.z, v.w};
#pragma unroll
    for (int m = 0; m < 4; ++m) {
        float lo = __uint_as_float(u[m] << 16);
        float hi = __uint_as_float(u[m] & 0xffff0000u);
        acc[2 * m]     += w * lo;
        acc[2 * m + 1] += w * hi;
    }
}

// ---- paired gather for two nodes of a chunk.
//      Indices come from the per-wave LDS slab (staged coalesced once per chunk);
//      4 independent P-row streams + 2 self-loop rows in flight.
//      On return, every lane holds in accA/accB the neighbor-sum (incl. self)
//      for features c*8 .. c*8+7. ----
__device__ __forceinline__ void gather_pair(float accA[8], float accB[8],
                                            const bf16* __restrict__ P,
                                            const int* slab,
                                            const int* __restrict__ csr_src, int e0,
                                            int begA, int endA, int begB, int endB,
                                            int nodeA, int nodeB,
                                            int r, int c, int N) {
#pragma unroll
    for (int k = 0; k < 8; ++k) { accA[k] = 0.f; accB[k] = 0.f; }
    // self-loop rows: independent loads, issue first
    uint4 vsA = make_uint4(0u, 0u, 0u, 0u), vsB = make_uint4(0u, 0u, 0u, 0u);
    if (nodeA < N) vsA = *(const uint4*)(P + (size_t)nodeA * 64 + c * 8);
    if (nodeB < N) vsB = *(const uint4*)(P + (size_t)nodeB * 64 + c * 8);
    int tA = endA - begA, tB = endB - begB;
    int tmax = tA > tB ? tA : tB;
    for (int i = 0; i < tmax; i += 16) {
        int pA0 = begA + i + r, pA1 = pA0 + 8;
        int pB0 = begB + i + r, pB1 = pB0 + 8;
        int okA0 = pA0 < endA, okA1 = pA1 < endA;
        int okB0 = pB0 < endB, okB1 = pB1 < endB;
        int qA0 = okA0 ? pA0 : begA;
        int qA1 = okA1 ? pA1 : begA;
        int qB0 = okB0 ? pB0 : begB;
        int qB1 = okB1 ? pB1 : begB;
        // index fetch from LDS slab (values are always valid node ids — staged clamped)
        int sA0 = slab[qA0 < SLAB ? qA0 : 0];
        int sA1 = slab[qA1 < SLAB ? qA1 : 0];
        int sB0 = slab[qB0 < SLAB ? qB0 : 0];
        int sB1 = slab[qB1 < SLAB ? qB1 : 0];
        if (qA0 >= SLAB) sA0 = csr_src[e0 + qA0];   // overflow fallback (stat. never)
        if (qA1 >= SLAB) sA1 = csr_src[e0 + qA1];
        if (qB0 >= SLAB) sB0 = csr_src[e0 + qB0];
        if (qB1 >= SLAB) sB1 = csr_src[e0 + qB1];
        uint4 vA0 = *(const uint4*)(P + (size_t)sA0 * 64 + c * 8);
        uint4 vA1 = *(const uint4*)(P + (size_t)sA1 * 64 + c * 8);
        uint4 vB0 = *(const uint4*)(P + (size_t)sB0 * 64 + c * 8);
        uint4 vB1 = *(const uint4*)(P + (size_t)sB1 * 64 + c * 8);
        acc_bf8(accA, vA0, okA0 ? 1.f : 0.f);
        acc_bf8(accA, vA1, okA1 ? 1.f : 0.f);
        acc_bf8(accB, vB0, okB0 ? 1.f : 0.f);
        acc_bf8(accB, vB1, okB1 ? 1.f : 0.f);
    }
    // butterfly-reduce across the 8 r-groups (lane bits 3..5)
#pragma unroll
    for (int mask = 8; mask <= 32; mask <<= 1) {
#pragma unroll
        for (int k = 0; k < 8; ++k) {
            accA[k] += __shfl_xor(accA[k], mask);
            accB[k] += __shfl_xor(accB[k], mask);
        }
    }
    // self-loop chunk (added once per lane, after reduction)
    acc_bf8(accA, vsA, 1.f);
    acc_bf8(accB, vsB, 1.f);
}

// ---- layer1 aggregate + fused layer2 projection (chunk-per-wave) ----
__global__ __launch_bounds__(256, 4) void agg_proj_kernel(const bf16* __restrict__ P1,
                                                          const int* __restrict__ row_start,
                                                          const int* __restrict__ csr_src,
                                                          const float* __restrict__ dinv,
                                                          const float* __restrict__ b1,
                                                          const float* __restrict__ W2,
                                                          bf16* __restrict__ P2, int N, int E) {
    __shared__ float Wl[4096];
    __shared__ int slab_all[4][SLAB];
    for (int i = threadIdx.x; i < 4096; i += 256) Wl[i] = W2[i];
    __syncthreads();
    int lane = threadIdx.x & 63;
    int wslot = threadIdx.x >> 6;
    int* slab = slab_all[wslot];
    int wid = blockIdx.x * 4 + wslot;
    int base = wid * CHUNK;
    if (base >= N) return;
    int r = lane >> 3, c = lane & 7;

    // chunk row bounds (9 contiguous ints, one lane-parallel load) + dinv
    int rsv = 0;
    if (lane <= CHUNK) { int idx = base + lane; rsv = row_start[idx > N ? N : idx]; }
    float dvv = 0.f;
    if (lane < CHUNK) { int idx = base + lane; dvv = dinv[idx < N ? idx : N - 1]; }
    int e0 = __shfl(rsv, 0);
    int nE = __shfl(rsv, CHUNK) - e0;

    // stage the chunk's edge slice into LDS, coalesced (clamped source => valid ids)
    int cap = nE < SLAB ? nE : SLAB;
    for (int i = 0; i < cap; i += 64) {
        int gidx = e0 + i + lane;
        slab[i + lane] = csr_src[gidx < E ? gidx : E - 1];
    }

    float bb[8];
#pragma unroll
    for (int k = 0; k < 8; ++k) bb[k] = b1[c * 8 + k];

#pragma unroll
    for (int j = 0; j < CHUNK; j += 2) {
        int nodeA = base + j, nodeB = base + j + 1;
        int bA = __shfl(rsv, j)     - e0;
        int eA = __shfl(rsv, j + 1) - e0;
        int eB = __shfl(rsv, j + 2) - e0;
        float accA[8], accB[8];
        gather_pair(accA, accB, P1, slab, csr_src, e0, bA, eA, eA, eB,
                    nodeA, nodeB, r, c, N);
        float dvA = __shfl(dvv, j), dvB = __shfl(dvv, j + 1);
        float hA[8], hB[8];
#pragma unroll
        for (int k = 0; k < 8; ++k) {
            hA[k] = fmaxf(accA[k] * dvA + bb[k], 0.f);
            hB[k] = fmaxf(accB[k] * dvB + bb[k], 0.f);
        }
        // fused projection, one Wl read per two FMAs
        float a2A = 0.f, a2B = 0.f;
#pragma unroll
        for (int c2 = 0; c2 < 8; ++c2) {
#pragma unroll
            for (int jj = 0; jj < 8; ++jj) {
                float w = Wl[(c2 * 8 + jj) * 64 + lane];
                a2A += __shfl(hA[jj], c2) * w;
                a2B += __shfl(hB[jj], c2) * w;
            }
        }
        if (nodeA < N) P2[(size_t)nodeA * 64 + lane] = __float2bfloat16(a2A * dvA);
        if (nodeB < N) P2[(size_t)nodeB * 64 + lane] = __float2bfloat16(a2B * dvB);
    }
}

// ---- layer2 aggregate + fused mean-pool accumulation (chunk-per-wave) ----
__global__ __launch_bounds__(256, 4) void agg_pool_kernel(const bf16* __restrict__ P2,
                                                          const int* __restrict__ row_start,
                                                          const int* __restrict__ csr_src,
                                                          const float* __restrict__ dinv,
                                                          const float* __restrict__ b2,
                                                          const int* __restrict__ batch,
                                                          float* __restrict__ out_h,
                                                          float* __restrict__ accum, int N, int E) {
    __shared__ int slab_all[4][SLAB];
    int lane = threadIdx.x & 63;
    int wslot = threadIdx.x >> 6;
    int* slab = slab_all[wslot];
    int wid = blockIdx.x * 4 + wslot;
    int base = wid * CHUNK;
    if (base >= N) return;
    int r = lane >> 3, c = lane & 7;

    int rsv = 0;
    if (lane <= CHUNK) { int idx = base + lane; rsv = row_start[idx > N ? N : idx]; }
    float dvv = 0.f; int bvv = 0;
    if (lane < CHUNK) {
        int idx = base + lane; int ii = idx < N ? idx : N - 1;
        dvv = dinv[ii]; bvv = batch[ii];
    }
    int e0 = __shfl(rsv, 0);
    int nE = __shfl(rsv, CHUNK) - e0;
    int cap = nE < SLAB ? nE : SLAB;
    for (int i = 0; i < cap; i += 64) {
        int gidx = e0 + i + lane;
        slab[i + lane] = csr_src[gidx < E ? gidx : E - 1];
    }

    float bb[8];
#pragma unroll
    for (int k = 0; k < 8; ++k) bb[k] = b2[c * 8 + k];
    // transpose source lane: lane l pulls feature l from lane src
    int src = ((lane & 7) << 3) | (lane >> 3);

    float poolv = 0.f;
    int curg = max(0, min(__shfl(bvv, 0), NGRAPH - 1));

#pragma unroll
    for (int j = 0; j < CHUNK; j += 2) {
        int nodeA = base + j, nodeB = base + j + 1;
        int bA = __shfl(rsv, j)     - e0;
        int eA = __shfl(rsv, j + 1) - e0;
        int eB = __shfl(rsv, j + 2) - e0;
        float accA[8], accB[8];
        gather_pair(accA, accB, P2, slab, csr_src, e0, bA, eA, eA, eB,
                    nodeA, nodeB, r, c, N);
        float dvA = __shfl(dvv, j), dvB = __shfl(dvv, j + 1);
        float hA[8], hB[8];
#pragma unroll
        for (int k = 0; k < 8; ++k) {
            hA[k] = accA[k] * dvA + bb[k];
            hB[k] = accB[k] * dvB + bb[k];
        }
        // in-register transpose: lane l ends up holding feature l
        float valA = 0.f, valB = 0.f;
#pragma unroll
        for (int k = 0; k < 8; ++k) {
            float tAv = __shfl(hA[k], src);
            float tBv = __shfl(hB[k], src);
            valA = ((lane & 7) == k) ? tAv : valA;
            valB = ((lane & 7) == k) ? tBv : valB;
        }
        if (nodeA < N) {
            out_h[(size_t)nodeA * 64 + lane] = valA;
            int g = max(0, min(__shfl(bvv, j), NGRAPH - 1));
            if (g != curg) { atomicAdd(&accum[curg * 64 + lane], poolv); poolv = 0.f; curg = g; }
            poolv += valA;
        }
        if (nodeB < N) {
            out_h[(size_t)nodeB * 64 + lane] = valB;
            int g = max(0, min(__shfl(bvv, j + 1), NGRAPH - 1));
            if (g != curg) { atomicAdd(&accum[curg * 64 + lane], poolv); poolv = 0.f; curg = g; }
            poolv += valB;
        }
    }
    atomicAdd(&accum[curg * 64 + lane], poolv);   // flush chunk remainder
}

// ---------------- finalize pool (divide by count) + classifier head ----------------
__device__ __forceinline__ int lower_bound_dev(const int* a, int n, int key) {
    int lo = 0, hi = n;
    while (lo < hi) {
        int mid = (lo + hi) >> 1;
        if (a[mid] < key) lo = mid + 1; else hi = mid;
    }
    return lo;
}

__global__ __launch_bounds__(64) void final_kernel(const float* __restrict__ accum,
                                                   const int* __restrict__ batch,
                                                   const float* __restrict__ Wc1,
                                                   const float* __restrict__ bc1,
                                                   const float* __restrict__ Wc2,
                                                   const float* __restrict__ bc2,
                                                   float* __restrict__ out_reps,
                                                   float* __restrict__ out_logits, int N) {
    __shared__ float rep[64];
    __shared__ float t[64];
    int g = blockIdx.x;
    int f = threadIdx.x;
    int lo = lower_bound_dev(batch, N, g);
    int hi = lower_bound_dev(batch, N, g + 1);
    float cnt = (float)(hi - lo);
    float r = accum[g * 64 + f] / fmaxf(cnt, 1.f);
    out_reps[g * 64 + f] = r;
    rep[f] = r;
    __syncthreads();
    float acc = bc1[f];
#pragma unroll
    for (int k = 0; k < 64; ++k) acc += rep[k] * Wc1[k * 64 + f];
    t[f] = fmaxf(acc, 0.f);
    __syncthreads();
    if (f < 16) {
        float a2 = bc2[f];
#pragma unroll
        for (int k = 0; k < 64; ++k) a2 += t[k] * Wc2[k * 16 + f];
        out_logits[g * 16 + f] = a2;
    }
}

extern "C" void kernel_launch(void* const* d_in, const int* in_sizes, int n_in,
                              void* d_out, int out_size, void* d_ws, size_t ws_size,
                              hipStream_t stream) {
    const float* x    = (const float*)d_in[0];
    const int*   ei   = (const int*)d_in[1];
    const int*   batch= (const int*)d_in[2];
    const float* W1   = (const float*)d_in[3];
    const float* b1   = (const float*)d_in[4];
    const float* W2   = (const float*)d_in[5];
    const float* b2   = (const float*)d_in[6];
    const float* Wc1  = (const float*)d_in[7];
    const float* bc1  = (const float*)d_in[8];
    const float* Wc2  = (const float*)d_in[9];
    const float* bc2  = (const float*)d_in[10];

    const int N = in_sizes[2];          // 50000
    const int E = in_sizes[1] / 2;      // 800000

    // ---- workspace layout (~7.3 MB) ----
    char* ws = (char*)d_ws;
    size_t off = 0;
    auto alloc = [&](size_t bytes) { void* p = ws + off; off += (bytes + 255) & ~(size_t)255; return p; };
    int*   deg       = (int*)  alloc((size_t)N * 4);
    int*   cursor    = (int*)  alloc((size_t)N * 4);
    float* accum     = (float*)alloc((size_t)NGRAPH * 64 * 4);
    size_t zero_bytes = off;                       // deg + cursor + accum start at 0
    float* dinv      = (float*)alloc((size_t)N * 4);
    int*   row_start = (int*)  alloc((size_t)(N + 1) * 4);
    int*   bsum      = (int*)  alloc(1024);
    int*   boff      = (int*)  alloc(1024);
    int*   csr_src   = (int*)  alloc((size_t)E * 4);
    bf16*  P1        = (bf16*) alloc((size_t)N * 64 * 2);
    bf16*  P2        = (bf16*) alloc((size_t)N * 64 * 2);
    (void)ws_size; (void)n_in; (void)out_size;

    float* out_h      = (float*)d_out;                      // [N,64]
    float* out_reps   = out_h + (size_t)N * 64;             // [128,64]
    float* out_logits = out_reps + (size_t)NGRAPH * 64;     // [128,16]

    int nbE = (E + 255) / 256;
    int nbN = (N + 255) / 256;
    const int GS = 2048;                 // grid-stride blocks for proj

    // chunked agg kernels: one wave per CHUNK contiguous nodes
    int nwaves_c = (N + CHUNK - 1) / CHUNK;
    int nblk_c   = (nwaves_c + 3) / 4;

    hipMemsetAsync(d_ws, 0, zero_bytes, stream);
    deg_kernel<<<nbE, 256, 0, stream>>>(ei, deg, E, N);
    scan1_kernel<<<nbN, 256, 0, stream>>>(deg, bsum, N);
    scan2_kernel<<<1, 256, 0, stream>>>(bsum, boff, nbN);
    scan3_kernel<<<nbN, 256, 0, stream>>>(deg, boff, row_start, dinv, N);
    fill_kernel<<<nbE, 256, 0, stream>>>(ei, row_start, cursor, csr_src, E, N);

    proj_kernel<<<GS, 256, 0, stream>>>(x, W1, dinv, P1, N);
    agg_proj_kernel<<<nblk_c, 256, 0, stream>>>(P1, row_start, csr_src, dinv, b1, W2, P2, N, E);
    agg_pool_kernel<<<nblk_c, 256, 0, stream>>>(P2, row_start, csr_src, dinv, b2, batch,
                                                out_h, accum, N, E);
    final_kernel<<<NGRAPH, 64, 0, stream>>>(accum, batch, Wc1, bc1, Wc2, bc2,
                                            out_reps, out_logits, N);
}

// Round 3
// 325.104 us; speedup vs baseline: 1.4860x; 1.4860x over previous
//
#include <hip/hip_runtime.h>
#include <hip/hip_bf16.h>

typedef __hip_bfloat16 bf16;

#define NGRAPH 128
#define CHUNK 8      // nodes per wave in the agg kernels
#define SLAB 256     // per-wave staged edge-index capacity (avg chunk = 128)

// ---------------- degree histogram ----------------
__global__ __launch_bounds__(256) void deg_kernel(const int* __restrict__ ei,
                                                  int* __restrict__ deg, int E, int N) {
    int e = blockIdx.x * 256 + threadIdx.x;
    if (e < E) {
        int d = ei[E + e];                 // dst = ei[1][e]
        d = max(0, min(d, N - 1));
        atomicAdd(&deg[d], 1);
    }
}

// ---------------- scan: per-block sums ----------------
__global__ __launch_bounds__(256) void scan1_kernel(const int* __restrict__ deg,
                                                    int* __restrict__ bsum, int N) {
    __shared__ int tmp[256];
    int i = blockIdx.x * 256 + threadIdx.x;
    tmp[threadIdx.x] = (i < N) ? deg[i] : 0;
    __syncthreads();
    for (int off = 128; off > 0; off >>= 1) {
        if (threadIdx.x < off) tmp[threadIdx.x] += tmp[threadIdx.x + off];
        __syncthreads();
    }
    if (threadIdx.x == 0) bsum[blockIdx.x] = tmp[0];
}

// ---------------- scan: exclusive scan of block sums ----------------
__global__ __launch_bounds__(256) void scan2_kernel(const int* __restrict__ bsum,
                                                    int* __restrict__ boff, int nb) {
    __shared__ int tmp[256];
    __shared__ int carry;
    int tid = threadIdx.x;
    if (tid == 0) carry = 0;
    __syncthreads();
    for (int base = 0; base < nb; base += 256) {
        int i = base + tid;
        int v = (i < nb) ? bsum[i] : 0;
        tmp[tid] = v;
        __syncthreads();
        for (int off = 1; off < 256; off <<= 1) {
            int t = (tid >= off) ? tmp[tid - off] : 0;
            __syncthreads();
            tmp[tid] += t;
            __syncthreads();
        }
        if (i < nb) boff[i] = carry + tmp[tid] - v;
        __syncthreads();
        if (tid == 0) carry += tmp[255];
        __syncthreads();
    }
}

// ---------------- scan: per-element row_start + dinv ----------------
__global__ __launch_bounds__(256) void scan3_kernel(const int* __restrict__ deg,
                                                    const int* __restrict__ boff,
                                                    int* __restrict__ row_start,
                                                    float* __restrict__ dinv, int N) {
    __shared__ int tmp[256];
    int i = blockIdx.x * 256 + threadIdx.x;
    int v = (i < N) ? deg[i] : 0;
    tmp[threadIdx.x] = v;
    __syncthreads();
    for (int off = 1; off < 256; off <<= 1) {
        int t = (threadIdx.x >= off) ? tmp[threadIdx.x - off] : 0;
        __syncthreads();
        tmp[threadIdx.x] += t;
        __syncthreads();
    }
    if (i < N) {
        int excl = tmp[threadIdx.x] - v;
        int rs = boff[blockIdx.x] + excl;
        row_start[i] = rs;
        if (i == N - 1) row_start[N] = rs + v;
        dinv[i] = rsqrtf((float)(v + 1));   // +1 self loop
    }
}

// ---------------- CSR fill (dst-sorted src list) ----------------
__global__ __launch_bounds__(256) void fill_kernel(const int* __restrict__ ei,
                                                   const int* __restrict__ row_start,
                                                   int* __restrict__ cursor,
                                                   int* __restrict__ csr_src, int E, int N) {
    int e = blockIdx.x * 256 + threadIdx.x;
    if (e < E) {
        int s = ei[e];     s = max(0, min(s, N - 1));
        int d = ei[E + e]; d = max(0, min(d, N - 1));
        int pos = row_start[d] + atomicAdd(&cursor[d], 1);
        if (pos >= 0 && pos < E) csr_src[pos] = s;
    }
}

// ---------------- P1 = (x @ W1) * dinv  (wave-per-node-pair, grid-stride) ----------------
__global__ __launch_bounds__(256) void proj_kernel(const float* __restrict__ A,
                                                   const float* __restrict__ W,
                                                   const float* __restrict__ dinv,
                                                   bf16* __restrict__ P, int N) {
    __shared__ float Wl[4096];
    for (int i = threadIdx.x; i < 4096; i += 256) Wl[i] = W[i];
    __syncthreads();
    int lane = threadIdx.x & 63;
    int wid = (blockIdx.x * 256 + threadIdx.x) >> 6;
    int nwaves = (gridDim.x * 256) >> 6;
    int npairs = (N + 1) >> 1;
    for (int p = wid; p < npairs; p += nwaves) {
        int n0 = p * 2, n1 = n0 + 1;
        float a0 = A[(size_t)n0 * 64 + lane];
        float a1 = (n1 < N) ? A[(size_t)n1 * 64 + lane] : 0.f;
        float s0 = 0.f, s1 = 0.f;
#pragma unroll
        for (int k = 0; k < 64; ++k) {
            float w = Wl[k * 64 + lane];          // one LDS read feeds both nodes
            s0 += __shfl(a0, k) * w;
            s1 += __shfl(a1, k) * w;
        }
        P[(size_t)n0 * 64 + lane] = __float2bfloat16(s0 * dinv[n0]);
        if (n1 < N) P[(size_t)n1 * 64 + lane] = __float2bfloat16(s1 * dinv[n1]);
    }
}

// ---- unpack uint4 (8 bf16) and accumulate with weight w ----
__device__ __forceinline__ void acc_bf8(float* acc, uint4 v, float w) {
    unsigned int u[4] = {v.x, v.y, v.z, v.w};
#pragma unroll
    for (int m = 0; m < 4; ++m) {
        float lo = __uint_as_float(u[m] << 16);
        float hi = __uint_as_float(u[m] & 0xffff0000u);
        acc[2 * m]     += w * lo;
        acc[2 * m + 1] += w * hi;
    }
}

// ---- single-node wide gather (Round-0 register profile) with LDS-slab indices.
//      8 rows per load instruction, 2 row-streams in flight; indices come from
//      the per-wave slab (staged coalesced once per chunk), overflow falls back
//      to global csr_src (statistically never: avg chunk = 128 < SLAB=256).
//      On return, EVERY lane holds in acc[0..7] the neighbor-sum for features
//      c*8 .. c*8+7 (c = lane&7). ----
__device__ __forceinline__ void gather_slab(float acc[8],
                                            const bf16* __restrict__ P,
                                            const int* slab,
                                            const int* __restrict__ csr_src, int e0,
                                            int beg, int end, int r, int c) {
#pragma unroll
    for (int k = 0; k < 8; ++k) acc[k] = 0.f;
    for (int i = beg; i < end; i += 16) {
        int r0 = i + r, r1 = i + 8 + r;
        int ok0 = r0 < end, ok1 = r1 < end;
        int q0 = ok0 ? r0 : beg;
        int q1 = ok1 ? r1 : beg;
        int s0 = slab[q0 < SLAB ? q0 : 0];
        int s1 = slab[q1 < SLAB ? q1 : 0];
        if (q0 >= SLAB) s0 = csr_src[e0 + q0];   // e0+q0 < row_start[N] = E, safe
        if (q1 >= SLAB) s1 = csr_src[e0 + q1];
        uint4 v0 = *(const uint4*)(P + (size_t)s0 * 64 + c * 8);
        uint4 v1 = *(const uint4*)(P + (size_t)s1 * 64 + c * 8);
        acc_bf8(acc, v0, ok0 ? 1.f : 0.f);
        acc_bf8(acc, v1, ok1 ? 1.f : 0.f);
    }
    // butterfly-reduce across the 8 r-groups (lane bits 3..5)
#pragma unroll
    for (int mask = 8; mask <= 32; mask <<= 1) {
#pragma unroll
        for (int k = 0; k < 8; ++k) acc[k] += __shfl_xor(acc[k], mask);
    }
}

// ---- layer1 aggregate + fused layer2 projection (chunk-per-wave, single-node body) ----
__global__ __launch_bounds__(256) void agg_proj_kernel(const bf16* __restrict__ P1,
                                                       const int* __restrict__ row_start,
                                                       const int* __restrict__ csr_src,
                                                       const float* __restrict__ dinv,
                                                       const float* __restrict__ b1,
                                                       const float* __restrict__ W2,
                                                       bf16* __restrict__ P2, int N, int E) {
    __shared__ float Wl[4096];
    __shared__ int slab_all[4][SLAB];
    for (int i = threadIdx.x; i < 4096; i += 256) Wl[i] = W2[i];
    __syncthreads();
    int lane = threadIdx.x & 63;
    int wslot = threadIdx.x >> 6;
    int* slab = slab_all[wslot];
    int wid = blockIdx.x * 4 + wslot;
    int base = wid * CHUNK;
    if (base >= N) return;
    int r = lane >> 3, c = lane & 7;

    // chunk row bounds (9 contiguous ints, one lane-parallel load) + dinv
    int rsv = 0;
    if (lane <= CHUNK) { int idx = base + lane; rsv = row_start[idx > N ? N : idx]; }
    float dvv = 0.f;
    if (lane < CHUNK) { int idx = base + lane; dvv = dinv[idx < N ? idx : N - 1]; }
    int e0 = __shfl(rsv, 0);
    int nE = __shfl(rsv, CHUNK) - e0;

    // stage the chunk's edge slice into LDS, coalesced (per-wave slab, no barrier needed)
    int cap = nE < SLAB ? nE : SLAB;
    for (int i = 0; i < cap; i += 64) {
        int gidx = e0 + i + lane;
        slab[i + lane] = csr_src[gidx < E ? gidx : E - 1];
    }

    float bb[8];
#pragma unroll
    for (int k = 0; k < 8; ++k) bb[k] = b1[c * 8 + k];

#pragma unroll 1
    for (int j = 0; j < CHUNK; ++j) {
        int node = base + j;
        if (node >= N) break;
        int beg = __shfl(rsv, j)     - e0;
        int end = __shfl(rsv, j + 1) - e0;
        float acc[8];
        gather_slab(acc, P1, slab, csr_src, e0, beg, end, r, c);
        // self-loop chunk (added once per lane, after reduction)
        uint4 vs = *(const uint4*)(P1 + (size_t)node * 64 + c * 8);
        acc_bf8(acc, vs, 1.f);
        float dv = __shfl(dvv, j);
        float h[8];
#pragma unroll
        for (int k = 0; k < 8; ++k) h[k] = fmaxf(acc[k] * dv + bb[k], 0.f);
        // fused projection: P2[node][lane] = (h1 @ W2)[lane] * dinv
        float a2 = 0.f;
#pragma unroll
        for (int c2 = 0; c2 < 8; ++c2) {
#pragma unroll
            for (int jj = 0; jj < 8; ++jj) {
                a2 += __shfl(h[jj], c2) * Wl[(c2 * 8 + jj) * 64 + lane];
            }
        }
        P2[(size_t)node * 64 + lane] = __float2bfloat16(a2 * dv);
    }
}

// ---- layer2 aggregate + fused mean-pool accumulation (chunk-per-wave, single-node body) ----
__global__ __launch_bounds__(256) void agg_pool_kernel(const bf16* __restrict__ P2,
                                                       const int* __restrict__ row_start,
                                                       const int* __restrict__ csr_src,
                                                       const float* __restrict__ dinv,
                                                       const float* __restrict__ b2,
                                                       const int* __restrict__ batch,
                                                       float* __restrict__ out_h,
                                                       float* __restrict__ accum, int N, int E) {
    __shared__ int slab_all[4][SLAB];
    int lane = threadIdx.x & 63;
    int wslot = threadIdx.x >> 6;
    int* slab = slab_all[wslot];
    int wid = blockIdx.x * 4 + wslot;
    int base = wid * CHUNK;
    if (base >= N) return;
    int r = lane >> 3, c = lane & 7;

    int rsv = 0;
    if (lane <= CHUNK) { int idx = base + lane; rsv = row_start[idx > N ? N : idx]; }
    float dvv = 0.f; int bvv = 0;
    if (lane < CHUNK) {
        int idx = base + lane; int ii = idx < N ? idx : N - 1;
        dvv = dinv[ii]; bvv = batch[ii];
    }
    int e0 = __shfl(rsv, 0);
    int nE = __shfl(rsv, CHUNK) - e0;
    int cap = nE < SLAB ? nE : SLAB;
    for (int i = 0; i < cap; i += 64) {
        int gidx = e0 + i + lane;
        slab[i + lane] = csr_src[gidx < E ? gidx : E - 1];
    }

    float bb[8];
#pragma unroll
    for (int k = 0; k < 8; ++k) bb[k] = b2[c * 8 + k];
    // transpose source lane: lane l pulls feature l from lane src
    int src = ((lane & 7) << 3) | (lane >> 3);

    float poolv = 0.f;
    int curg = max(0, min(__shfl(bvv, 0), NGRAPH - 1));

#pragma unroll 1
    for (int j = 0; j < CHUNK; ++j) {
        int node = base + j;
        if (node >= N) break;
        int beg = __shfl(rsv, j)     - e0;
        int end = __shfl(rsv, j + 1) - e0;
        float acc[8];
        gather_slab(acc, P2, slab, csr_src, e0, beg, end, r, c);
        uint4 vs = *(const uint4*)(P2 + (size_t)node * 64 + c * 8);
        acc_bf8(acc, vs, 1.f);
        float dv = __shfl(dvv, j);
        float h[8];
#pragma unroll
        for (int k = 0; k < 8; ++k) h[k] = acc[k] * dv + bb[k];
        // in-register transpose: lane l ends up holding feature l
        float val = 0.f;
#pragma unroll
        for (int k = 0; k < 8; ++k) {
            float t = __shfl(h[k], src);
            val = ((lane & 7) == k) ? t : val;
        }
        out_h[(size_t)node * 64 + lane] = val;
        // run-batched pool: one atomic per graph-run within the chunk
        int g = max(0, min(__shfl(bvv, j), NGRAPH - 1));
        if (g != curg) { atomicAdd(&accum[curg * 64 + lane], poolv); poolv = 0.f; curg = g; }
        poolv += val;
    }
    atomicAdd(&accum[curg * 64 + lane], poolv);   // flush chunk remainder
}

// ---------------- finalize pool (divide by count) + classifier head ----------------
__device__ __forceinline__ int lower_bound_dev(const int* a, int n, int key) {
    int lo = 0, hi = n;
    while (lo < hi) {
        int mid = (lo + hi) >> 1;
        if (a[mid] < key) lo = mid + 1; else hi = mid;
    }
    return lo;
}

__global__ __launch_bounds__(64) void final_kernel(const float* __restrict__ accum,
                                                   const int* __restrict__ batch,
                                                   const float* __restrict__ Wc1,
                                                   const float* __restrict__ bc1,
                                                   const float* __restrict__ Wc2,
                                                   const float* __restrict__ bc2,
                                                   float* __restrict__ out_reps,
                                                   float* __restrict__ out_logits, int N) {
    __shared__ float rep[64];
    __shared__ float t[64];
    int g = blockIdx.x;
    int f = threadIdx.x;
    int lo = lower_bound_dev(batch, N, g);
    int hi = lower_bound_dev(batch, N, g + 1);
    float cnt = (float)(hi - lo);
    float r = accum[g * 64 + f] / fmaxf(cnt, 1.f);
    out_reps[g * 64 + f] = r;
    rep[f] = r;
    __syncthreads();
    float acc = bc1[f];
#pragma unroll
    for (int k = 0; k < 64; ++k) acc += rep[k] * Wc1[k * 64 + f];
    t[f] = fmaxf(acc, 0.f);
    __syncthreads();
    if (f < 16) {
        float a2 = bc2[f];
#pragma unroll
        for (int k = 0; k < 64; ++k) a2 += t[k] * Wc2[k * 16 + f];
        out_logits[g * 16 + f] = a2;
    }
}

extern "C" void kernel_launch(void* const* d_in, const int* in_sizes, int n_in,
                              void* d_out, int out_size, void* d_ws, size_t ws_size,
                              hipStream_t stream) {
    const float* x    = (const float*)d_in[0];
    const int*   ei   = (const int*)d_in[1];
    const int*   batch= (const int*)d_in[2];
    const float* W1   = (const float*)d_in[3];
    const float* b1   = (const float*)d_in[4];
    const float* W2   = (const float*)d_in[5];
    const float* b2   = (const float*)d_in[6];
    const float* Wc1  = (const float*)d_in[7];
    const float* bc1  = (const float*)d_in[8];
    const float* Wc2  = (const float*)d_in[9];
    const float* bc2  = (const float*)d_in[10];

    const int N = in_sizes[2];          // 50000
    const int E = in_sizes[1] / 2;      // 800000

    // ---- workspace layout (~7.3 MB) ----
    char* ws = (char*)d_ws;
    size_t off = 0;
    auto alloc = [&](size_t bytes) { void* p = ws + off; off += (bytes + 255) & ~(size_t)255; return p; };
    int*   deg       = (int*)  alloc((size_t)N * 4);
    int*   cursor    = (int*)  alloc((size_t)N * 4);
    float* accum     = (float*)alloc((size_t)NGRAPH * 64 * 4);
    size_t zero_bytes = off;                       // deg + cursor + accum start at 0
    float* dinv      = (float*)alloc((size_t)N * 4);
    int*   row_start = (int*)  alloc((size_t)(N + 1) * 4);
    int*   bsum      = (int*)  alloc(1024);
    int*   boff      = (int*)  alloc(1024);
    int*   csr_src   = (int*)  alloc((size_t)E * 4);
    bf16*  P1        = (bf16*) alloc((size_t)N * 64 * 2);
    bf16*  P2        = (bf16*) alloc((size_t)N * 64 * 2);
    (void)ws_size; (void)n_in; (void)out_size;

    float* out_h      = (float*)d_out;                      // [N,64]
    float* out_reps   = out_h + (size_t)N * 64;             // [128,64]
    float* out_logits = out_reps + (size_t)NGRAPH * 64;     // [128,16]

    int nbE = (E + 255) / 256;
    int nbN = (N + 255) / 256;
    const int GS = 2048;                 // grid-stride blocks for proj

    // chunked agg kernels: one wave per CHUNK contiguous nodes
    int nwaves_c = (N + CHUNK - 1) / CHUNK;
    int nblk_c   = (nwaves_c + 3) / 4;

    hipMemsetAsync(d_ws, 0, zero_bytes, stream);
    deg_kernel<<<nbE, 256, 0, stream>>>(ei, deg, E, N);
    scan1_kernel<<<nbN, 256, 0, stream>>>(deg, bsum, N);
    scan2_kernel<<<1, 256, 0, stream>>>(bsum, boff, nbN);
    scan3_kernel<<<nbN, 256, 0, stream>>>(deg, boff, row_start, dinv, N);
    fill_kernel<<<nbE, 256, 0, stream>>>(ei, row_start, cursor, csr_src, E, N);

    proj_kernel<<<GS, 256, 0, stream>>>(x, W1, dinv, P1, N);
    agg_proj_kernel<<<nblk_c, 256, 0, stream>>>(P1, row_start, csr_src, dinv, b1, W2, P2, N, E);
    agg_pool_kernel<<<nblk_c, 256, 0, stream>>>(P2, row_start, csr_src, dinv, b2, batch,
                                                out_h, accum, N, E);
    final_kernel<<<NGRAPH, 64, 0, stream>>>(accum, batch, Wc1, bc1, Wc2, bc2,
                                            out_reps, out_logits, N);
}